// Round 4
// baseline (387.162 us; speedup 1.0000x reference)
//
#include <hip/hip_runtime.h>

// Event-warp + bilinear splat.
//   NEW path: single-pass duplicate-scatter into per-tile fixed-cap regions
//             (no histogram/scan), then 1x-read ownership-tile splat.
//   OLD path (fallback if ws too small): round-3 hist/scan/scatter/splat.
// Inputs (setup_inputs order):
//   d_in[0] flow  : float32 [B,2,H,W]   (ch0 = x-flow, ch1 = y-flow)
//   d_in[1] ts    : float32 [B,N,1]
//   d_in[2] ev_y  : int32   [B,N]
//   d_in[3] ev_x  : int32   [B,N]
//   d_in[4] pol   : int32   [B,N]  (1 = pos, 0 = neg)
// Output: float32 [B,4,H,W] = (iwe_pos, iwe_neg, iwe_pos_ts, iwe_neg_ts)

#define IMG_H 480
#define IMG_W 640

// Ownership (splat) tiles: 16x32
#define OT_H 16
#define OT_W 32
#define OTY (IMG_H / OT_H)        // 30
#define OTX (IMG_W / OT_W)        // 20
#define OT_PER_B (OTY * OTX)      // 600
#define NB 4                      // expected batch
#define NT (NB * OT_PER_B)        // 2400

#define ACC_PLANE (OT_H * OT_W)   // 512 floats
#define ACC_TOT (4 * ACC_PLANE)   // 2048 floats = 8 KB LDS

// NEW-path ws layout (byte offsets)
#define SPILL_CAP 65536
#define WS_CURS 0                       // NT * u32 = 9600 B
#define WS_SPILLCNT 9600                // 1 * u32
#define WS_SPILL 16384                  // SPILL_CAP * float4 = 1 MB
#define WS_RECS (16384 + SPILL_CAP * 16)  // NT * cap * float4

// OLD-path (round-3) coarse buckets: 32x64
#define CB_H 32
#define CB_W 64
#define CBY (IMG_H / CB_H)        // 15
#define CBX (IMG_W / CB_W)        // 10
#define CB_PER_B (CBY * CBX)      // 150
#define NCB 600
#define OWS_HIST 0
#define OWS_OFFS 4096
#define OWS_CURS 8192
#define OWS_RECS 16384

#define SENTINEL 0xFFFFFFFFu

// ---------------------------------------------------------------------------
// Warp one event. Events sit on integer pixels -> flow bilinear gather
// degenerates to a direct lookup.
__device__ __forceinline__ void
warp_event(const float* __restrict__ flow, const float* __restrict__ ts,
           const int* __restrict__ ev_y, const int* __restrict__ ev_x,
           const int* __restrict__ pol, int i, int b,
           float& wy, float& wx, float& nts, int& p) {
    const int y = ev_y[i];
    const int x = ev_x[i];
    const float t = ts[i];
    p = pol[i];
    const float* fb = flow + (size_t)b * 2 * IMG_H * IMG_W;
    const int pix = y * IMG_W + x;
    const float fx = fb[pix];                  // ch0 = x-flow
    const float fy = fb[IMG_H * IMG_W + pix];  // ch1 = y-flow
    const float dt = 1.0f - t;                 // TREF - ts
    wy = (float)y + dt * fy;
    wx = (float)x + dt * fx;
    nts = 1.0f - fabsf(1.0f - t);
}

// ===========================================================================
// NEW PATH
// ===========================================================================

// Pass 1: warp each event, write one record copy per ownership tile that owns
// at least one in-image bilinear corner (expected ~1.1 copies/event).
__global__ void __launch_bounds__(256)
build_kernel(const float* __restrict__ flow, const float* __restrict__ ts,
             const int* __restrict__ ev_y, const int* __restrict__ ev_x,
             const int* __restrict__ pol,
             unsigned* __restrict__ curs, unsigned* __restrict__ spillcnt,
             float4* __restrict__ spill, float4* __restrict__ recs,
             int N, int cap) {
    const int b = blockIdx.y;
    const int idx = blockIdx.x * 256 + threadIdx.x;
    if (idx >= N) return;
    const int i = b * N + idx;

    float wy, wx, nts; int p;
    warp_event(flow, ts, ev_y, ev_x, pol, i, b, wy, wx, nts, p);

    const int iy0 = (int)floorf(wy);
    const int ix0 = (int)floorf(wx);

    // destination tile rows/cols owning the in-image corners
    int rys[2]; int nry = 0;
    if (iy0 >= 0 && iy0 < IMG_H) rys[nry++] = iy0 >> 4;
    if (iy0 + 1 >= 0 && iy0 + 1 < IMG_H) {
        const int r = (iy0 + 1) >> 4;
        if (nry == 0 || r != rys[0]) rys[nry++] = r;
    }
    int rxs[2]; int nrx = 0;
    if (ix0 >= 0 && ix0 < IMG_W) rxs[nrx++] = ix0 >> 5;
    if (ix0 + 1 >= 0 && ix0 + 1 < IMG_W) {
        const int r = (ix0 + 1) >> 5;
        if (nrx == 0 || r != rxs[0]) rxs[nrx++] = r;
    }
    if (nry == 0 || nrx == 0) return;

    float4 rec;
    rec.x = wy; rec.y = wx; rec.z = nts;
    rec.w = __uint_as_float((unsigned)((b << 1) | (p & 1)));

    for (int a = 0; a < nry; ++a) {
        for (int c = 0; c < nrx; ++c) {
            const int tile = (b * OTY + rys[a]) * OTX + rxs[c];
            const unsigned rank = atomicAdd(&curs[tile], 1u);
            if (rank < (unsigned)cap) {
                recs[(size_t)tile * cap + rank] = rec;
            } else {
                const unsigned s = atomicAdd(spillcnt, 1u);
                if (s < SPILL_CAP) spill[s] = rec;
            }
        }
    }
}

// Pass 2: one block per tile. Reads only its own records (1x redundancy,
// contiguous). LDS accumulate, plain float4 store-out (exclusive ownership).
__global__ void __launch_bounds__(256)
splat_own_kernel(const float4* __restrict__ recs, const unsigned* __restrict__ curs,
                 float* __restrict__ out, int cap) {
    __shared__ __align__(16) float acc[ACC_TOT];   // [4 planes][16][32]
    const int tile = blockIdx.x;
    const int tid = threadIdx.x;
    #pragma unroll
    for (int j = tid; j < ACC_TOT; j += 256) acc[j] = 0.0f;
    __syncthreads();

    const int b  = tile / OT_PER_B;
    const int rb = tile % OT_PER_B;
    const int sy = rb / OTX;
    const int sx = rb % OTX;

    const unsigned cnt = min(curs[tile], (unsigned)cap);
    const float4* base = recs + (size_t)tile * cap;
    for (unsigned i = tid; i < cnt; i += 256) {
        const float4 r = base[i];
        const float wy = r.x, wx = r.y, nts = r.z;
        const int p = (int)(__float_as_uint(r.w) & 1u);
        const float byf = floorf(wy), bxf = floorf(wx);
        const int iy0 = (int)byf, ix0 = (int)bxf;
        const float ay = wy - byf, ax = wx - bxf;
        const float wyv[2] = {1.0f - ay, ay};
        const float wxv[2] = {1.0f - ax, ax};
        float* accc = acc + (p ? 0 : 1) * ACC_PLANE;  // count plane
        float* acct = accc + 2 * ACC_PLANE;           // ts plane
        #pragma unroll
        for (int dy = 0; dy < 2; ++dy) {
            const int gy = iy0 + dy;
            if ((gy >> 4) != sy) continue;            // rejects OOB too
            #pragma unroll
            for (int dx = 0; dx < 2; ++dx) {
                const int gx = ix0 + dx;
                if ((gx >> 5) != sx) continue;
                const float w = wyv[dy] * wxv[dx];
                const int idx = (gy & (OT_H - 1)) * OT_W + (gx & (OT_W - 1));
                atomicAdd(&accc[idx], w);
                atomicAdd(&acct[idx], w * nts);
            }
        }
    }
    __syncthreads();

    const int y0 = sy * OT_H;
    const int x0 = sx * OT_W;
    const float4* acc4 = (const float4*)acc;
    float* outb = out + (size_t)b * 4 * IMG_H * IMG_W;
    #pragma unroll
    for (int q = tid; q < ACC_TOT / 4; q += 256) {
        const int plane = q / (ACC_PLANE / 4);
        const int rem   = q % (ACC_PLANE / 4);
        const int ry    = rem / (OT_W / 4);
        const int rx4   = rem % (OT_W / 4);
        float4* dst = (float4*)(outb + (size_t)plane * IMG_H * IMG_W
                                + (size_t)(y0 + ry) * IMG_W + x0 + rx4 * 4);
        *dst = acc4[q];
    }
}

// Pass 3: apply spill records (normally zero) with global atomics, after splat.
__global__ void __launch_bounds__(256)
spill_kernel(const float4* __restrict__ spill, const unsigned* __restrict__ spillcnt,
             float* __restrict__ out) {
    const unsigned n = min(*spillcnt, (unsigned)SPILL_CAP);
    const unsigned stride = gridDim.x * 256;
    for (unsigned i = blockIdx.x * 256 + threadIdx.x; i < n; i += stride) {
        const float4 r = spill[i];
        const unsigned meta = __float_as_uint(r.w);
        const int p = (int)(meta & 1u);
        const int b = (int)(meta >> 1);
        const float wy = r.x, wx = r.y, nts = r.z;
        const float byf = floorf(wy), bxf = floorf(wx);
        const int iy0 = (int)byf, ix0 = (int)bxf;
        const float ay = wy - byf, ax = wx - bxf;
        const float wyv[2] = {1.0f - ay, ay};
        const float wxv[2] = {1.0f - ax, ax};
        float* out_c = out + ((size_t)b * 4 + (p ? 0 : 1)) * IMG_H * IMG_W;
        float* out_t = out_c + 2 * IMG_H * IMG_W;
        #pragma unroll
        for (int dy = 0; dy < 2; ++dy) {
            const int gy = iy0 + dy;
            if (gy < 0 || gy >= IMG_H) continue;
            #pragma unroll
            for (int dx = 0; dx < 2; ++dx) {
                const int gx = ix0 + dx;
                if (gx < 0 || gx >= IMG_W) continue;
                const float w = wyv[dy] * wxv[dx];
                const int o = gy * IMG_W + gx;
                atomicAdd(out_c + o, w);
                atomicAdd(out_t + o, w * nts);
            }
        }
    }
}

// ===========================================================================
// OLD PATH (round-3 pipeline, fallback when ws too small for the new layout)
// ===========================================================================
__device__ __forceinline__ unsigned
compute_tile(const float* __restrict__ flow, const float* __restrict__ ts,
             const int* __restrict__ ev_y, const int* __restrict__ ev_x,
             const int* __restrict__ pol, int i, int N,
             float& wy, float& wx, float& nts, int& p) {
    const int b = i / N;
    warp_event(flow, ts, ev_y, ev_x, pol, i, b, wy, wx, nts, p);
    const int iy0 = (int)floorf(wy);
    const int ix0 = (int)floorf(wx);
    if (iy0 < -1 || iy0 > IMG_H - 1 || ix0 < -1 || ix0 > IMG_W - 1)
        return SENTINEL;
    const int cy = min(max(iy0, 0), IMG_H - 1);
    const int cx = min(max(ix0, 0), IMG_W - 1);
    return (unsigned)((b * CBY + cy / CB_H) * CBX + cx / CB_W);
}

__global__ void __launch_bounds__(256)
hist_kernel(const float* __restrict__ flow, const float* __restrict__ ts,
            const int* __restrict__ ev_y, const int* __restrict__ ev_x,
            const int* __restrict__ pol,
            unsigned* __restrict__ hist, int N, int total) {
    __shared__ unsigned lh[NCB];
    const int tid = threadIdx.x;
    for (int j = tid; j < NCB; j += 256) lh[j] = 0;
    __syncthreads();
    const int stride = gridDim.x * 256;
    for (int i = blockIdx.x * 256 + tid; i < total; i += stride) {
        float wy, wx, nts; int p;
        unsigned t = compute_tile(flow, ts, ev_y, ev_x, pol, i, N, wy, wx, nts, p);
        if (t != SENTINEL) atomicAdd(&lh[t], 1u);
    }
    __syncthreads();
    for (int j = tid; j < NCB; j += 256) {
        unsigned n = lh[j];
        if (n) atomicAdd(&hist[j], n);
    }
}

__global__ void __launch_bounds__(1024)
scan_kernel(const unsigned* __restrict__ hist, unsigned* __restrict__ offs,
            unsigned* __restrict__ curs) {
    __shared__ unsigned s[1024];
    const int t = threadIdx.x;
    s[t] = (t < NCB) ? hist[t] : 0u;
    __syncthreads();
    #pragma unroll
    for (int d = 1; d < 1024; d <<= 1) {
        unsigned v = (t >= d) ? s[t - d] : 0u;
        __syncthreads();
        s[t] += v;
        __syncthreads();
    }
    if (t < NCB) {
        unsigned excl = (t == 0) ? 0u : s[t - 1];
        offs[t] = excl;
        curs[t] = excl;
        if (t == NCB - 1) offs[NCB] = s[t];
    }
}

#define SC_IPT 8
#define SC_CHUNK (256 * SC_IPT)
__global__ void __launch_bounds__(256)
scatter_kernel(const float* __restrict__ flow, const float* __restrict__ ts,
               const int* __restrict__ ev_y, const int* __restrict__ ev_x,
               const int* __restrict__ pol,
               unsigned* __restrict__ curs, float4* __restrict__ recs,
               int N, int total) {
    __shared__ unsigned lhist[NCB];
    __shared__ unsigned lbase[NCB];
    const int tid = threadIdx.x;
    for (int j = tid; j < NCB; j += 256) lhist[j] = 0;
    __syncthreads();
    const int base_i = blockIdx.x * SC_CHUNK;
    unsigned tK[SC_IPT], rkK[SC_IPT];
    float wyK[SC_IPT], wxK[SC_IPT], ntsK[SC_IPT];
    int pK[SC_IPT];
    #pragma unroll
    for (int k = 0; k < SC_IPT; ++k) {
        const int i = base_i + k * 256 + tid;
        unsigned t = SENTINEL;
        if (i < total)
            t = compute_tile(flow, ts, ev_y, ev_x, pol, i, N,
                             wyK[k], wxK[k], ntsK[k], pK[k]);
        tK[k] = t;
        if (t != SENTINEL) rkK[k] = atomicAdd(&lhist[t], 1u);
    }
    __syncthreads();
    for (int j = tid; j < NCB; j += 256) {
        unsigned n = lhist[j];
        lbase[j] = n ? atomicAdd(&curs[j], n) : 0u;
    }
    __syncthreads();
    #pragma unroll
    for (int k = 0; k < SC_IPT; ++k) {
        const unsigned t = tK[k];
        if (t != SENTINEL) {
            float4 r;
            r.x = wyK[k]; r.y = wxK[k]; r.z = ntsK[k];
            r.w = __uint_as_float((unsigned)(pK[k] & 1));
            recs[lbase[t] + rkK[k]] = r;
        }
    }
}

__global__ void __launch_bounds__(256)
splat_cb_kernel(const float4* __restrict__ recs, const unsigned* __restrict__ offs,
                float* __restrict__ out) {
    __shared__ __align__(16) float acc[ACC_TOT];
    const int tile = blockIdx.x;
    const int tid = threadIdx.x;
    #pragma unroll
    for (int j = tid; j < ACC_TOT; j += 256) acc[j] = 0.0f;
    __syncthreads();
    const int b  = tile / OT_PER_B;
    const int rb = tile % OT_PER_B;
    const int sy = rb / OTX;
    const int sx = rb % OTX;
    const int ty_hi = sy >> 1, tx_hi = sx >> 1;
    const int ty_lo = ((sy & 1) == 0 && ty_hi > 0) ? ty_hi - 1 : ty_hi;
    const int tx_lo = ((sx & 1) == 0 && tx_hi > 0) ? tx_hi - 1 : tx_hi;
    for (int ty = ty_lo; ty <= ty_hi; ++ty) {
        const unsigned start = offs[(b * CBY + ty) * CBX + tx_lo];
        const unsigned end   = offs[(b * CBY + ty) * CBX + tx_hi + 1];
        for (unsigned i = start + tid; i < end; i += 256) {
            const float4 r = recs[i];
            const float wy = r.x, wx = r.y, nts = r.z;
            const int p = (int)(__float_as_uint(r.w) & 1u);
            const float byf = floorf(wy), bxf = floorf(wx);
            const int iy0 = (int)byf, ix0 = (int)bxf;
            const float ay = wy - byf, ax = wx - bxf;
            const float wyv[2] = {1.0f - ay, ay};
            const float wxv[2] = {1.0f - ax, ax};
            float* accc = acc + (p ? 0 : 1) * ACC_PLANE;
            float* acct = accc + 2 * ACC_PLANE;
            #pragma unroll
            for (int dy = 0; dy < 2; ++dy) {
                const int gy = iy0 + dy;
                if ((gy >> 4) != sy) continue;
                #pragma unroll
                for (int dx = 0; dx < 2; ++dx) {
                    const int gx = ix0 + dx;
                    if ((gx >> 5) != sx) continue;
                    const float w = wyv[dy] * wxv[dx];
                    const int idx = (gy & (OT_H - 1)) * OT_W + (gx & (OT_W - 1));
                    atomicAdd(&accc[idx], w);
                    atomicAdd(&acct[idx], w * nts);
                }
            }
        }
    }
    __syncthreads();
    const int y0 = sy * OT_H, x0 = sx * OT_W;
    const float4* acc4 = (const float4*)acc;
    float* outb = out + (size_t)b * 4 * IMG_H * IMG_W;
    #pragma unroll
    for (int q = tid; q < ACC_TOT / 4; q += 256) {
        const int plane = q / (ACC_PLANE / 4);
        const int rem   = q % (ACC_PLANE / 4);
        const int ry    = rem / (OT_W / 4);
        const int rx4   = rem % (OT_W / 4);
        float4* dst = (float4*)(outb + (size_t)plane * IMG_H * IMG_W
                                + (size_t)(y0 + ry) * IMG_W + x0 + rx4 * 4);
        *dst = acc4[q];
    }
}

// Last-resort fallback: direct global atomics (needs zeroed out).
__global__ void __launch_bounds__(256)
event_splat_fallback(const float* __restrict__ flow, const float* __restrict__ ts,
                     const int* __restrict__ ev_y, const int* __restrict__ ev_x,
                     const int* __restrict__ pol, float* __restrict__ out,
                     int N, int total) {
    const int i = blockIdx.x * blockDim.x + threadIdx.x;
    if (i >= total) return;
    float wy, wx, nts; int p;
    unsigned t = compute_tile(flow, ts, ev_y, ev_x, pol, i, N, wy, wx, nts, p);
    if (t == SENTINEL) return;
    const int b = i / N;
    const float byf = floorf(wy), bxf = floorf(wx);
    const int iy0 = (int)byf, ix0 = (int)bxf;
    const float ay = wy - byf, ax = wx - bxf;
    const float wyv[2] = {1.0f - ay, ay};
    const float wxv[2] = {1.0f - ax, ax};
    float* out_c = out + ((size_t)b * 4 + (p ? 0 : 1)) * IMG_H * IMG_W;
    float* out_t = out_c + 2 * IMG_H * IMG_W;
    #pragma unroll
    for (int dy = 0; dy < 2; ++dy) {
        const int gy = iy0 + dy;
        if (gy < 0 || gy >= IMG_H) continue;
        #pragma unroll
        for (int dx = 0; dx < 2; ++dx) {
            const int gx = ix0 + dx;
            if (gx < 0 || gx >= IMG_W) continue;
            const float w = wyv[dy] * wxv[dx];
            const int o = gy * IMG_W + gx;
            atomicAdd(out_c + o, w);
            atomicAdd(out_t + o, w * nts);
        }
    }
}

// ---------------------------------------------------------------------------
extern "C" void kernel_launch(void* const* d_in, const int* in_sizes, int n_in,
                              void* d_out, int out_size, void* d_ws, size_t ws_size,
                              hipStream_t stream) {
    const float* flow = (const float*)d_in[0];
    const float* ts   = (const float*)d_in[1];
    const int*   ev_y = (const int*)d_in[2];
    const int*   ev_x = (const int*)d_in[3];
    const int*   pol  = (const int*)d_in[4];
    float* out = (float*)d_out;

    const int total = in_sizes[2];                  // B*N
    const int B = out_size / (4 * IMG_H * IMG_W);
    const int N = total / B;
    char* ws = (char*)d_ws;

    // --- NEW path: needs NT*cap*16 bytes of record space; cap >= 704 keeps
    //     per-tile overflow probability ~0 (mean 548, sigma ~23.5).
    int cap = 0;
    if (ws_size > (size_t)WS_RECS)
        cap = (int)((ws_size - WS_RECS) / ((size_t)NT * sizeof(float4)));
    if (cap > 2048) cap = 2048;
    cap &= ~3;

    if (B == NB && cap >= 704) {
        unsigned* curs     = (unsigned*)(ws + WS_CURS);
        unsigned* spillcnt = (unsigned*)(ws + WS_SPILLCNT);
        float4*   spill    = (float4*)(ws + WS_SPILL);
        float4*   recs     = (float4*)(ws + WS_RECS);

        hipMemsetAsync(ws, 0, 16384, stream);   // curs + spillcnt

        dim3 bgrid((N + 255) / 256, B);
        build_kernel<<<bgrid, 256, 0, stream>>>(flow, ts, ev_y, ev_x, pol,
                                                curs, spillcnt, spill, recs,
                                                N, cap);
        splat_own_kernel<<<NT, 256, 0, stream>>>(recs, curs, out, cap);
        spill_kernel<<<16, 256, 0, stream>>>(spill, spillcnt, out);
        return;
    }

    // --- OLD path (round-3 pipeline)
    const size_t ws_needed_old = (size_t)OWS_RECS + (size_t)total * sizeof(float4);
    if (B * CB_PER_B == NCB && ws_size >= ws_needed_old) {
        unsigned* hist = (unsigned*)(ws + OWS_HIST);
        unsigned* offs = (unsigned*)(ws + OWS_OFFS);
        unsigned* curs = (unsigned*)(ws + OWS_CURS);
        float4*   recs = (float4*)(ws + OWS_RECS);

        hipMemsetAsync(hist, 0, NCB * sizeof(unsigned), stream);
        hist_kernel<<<300, 256, 0, stream>>>(flow, ts, ev_y, ev_x, pol, hist, N, total);
        scan_kernel<<<1, 1024, 0, stream>>>(hist, offs, curs);
        const int sc_blocks = (total + SC_CHUNK - 1) / SC_CHUNK;
        scatter_kernel<<<sc_blocks, 256, 0, stream>>>(flow, ts, ev_y, ev_x, pol,
                                                      curs, recs, N, total);
        splat_cb_kernel<<<B * OT_PER_B, 256, 0, stream>>>(recs, offs, out);
        return;
    }

    // --- last resort
    hipMemsetAsync(d_out, 0, (size_t)out_size * sizeof(float), stream);
    const int blocks = (total + 255) / 256;
    event_splat_fallback<<<blocks, 256, 0, stream>>>(flow, ts, ev_y, ev_x, pol,
                                                     out, N, total);
}

// Round 5
// 189.625 us; speedup vs baseline: 2.0417x; 2.0417x over previous
//
#include <hip/hip_runtime.h>

// Event-warp + bilinear splat.
//   NEW path: single-pass LDS-aggregated duplicate-scatter into per-tile
//             fixed-cap regions (padded cursors, one global atomic per
//             nonzero (block,tile)), then 1x-read ownership-tile splat.
//   OLD path (fallback): round-3 hist/scan/scatter/splat (known 209 us).
// Inputs (setup_inputs order):
//   d_in[0] flow  : float32 [B,2,H,W]   (ch0 = x-flow, ch1 = y-flow)
//   d_in[1] ts    : float32 [B,N,1]
//   d_in[2] ev_y  : int32   [B,N]
//   d_in[3] ev_x  : int32   [B,N]
//   d_in[4] pol   : int32   [B,N]  (1 = positive, 0 = negative)
// Output: float32 [B,4,H,W] = (iwe_pos, iwe_neg, iwe_pos_ts, iwe_neg_ts)

#define IMG_H 480
#define IMG_W 640

// Ownership (splat) tiles: 16x32
#define OT_H 16
#define OT_W 32
#define OTY (IMG_H / OT_H)        // 30
#define OTX (IMG_W / OT_W)        // 20
#define OT_PER_B (OTY * OTX)      // 600
#define NB 4                      // expected batch
#define NT (NB * OT_PER_B)        // 2400

#define ACC_PLANE (OT_H * OT_W)   // 512 floats
#define ACC_TOT (4 * ACC_PLANE)   // 2048 floats = 8 KB LDS

// NEW-path ws layout (byte offsets). Cursors padded: one per 64B line.
#define CURS_STRIDE 16                   // u32 stride -> 64 B
#define SPILL_CAP 32768
#define WS_CURS 0                        // NT * 64 B = 153600
#define WS_SPILLCNT (NT * 64)            // 153600, 4 B
#define WS_SPILL 163840                  // SPILL_CAP * 16 B = 512 KB
#define WS_RECS (163840 + SPILL_CAP * 16)  // NT * cap * float4

// build kernel batching
#define BD_IPT 8
#define BD_CHUNK (256 * BD_IPT)          // 2048 events per block
#define SIDE_CAP 448                     // expected ~196 +- 13 per block

// OLD-path (round-3) coarse buckets: 32x64
#define CB_H 32
#define CB_W 64
#define CBY (IMG_H / CB_H)
#define CBX (IMG_W / CB_W)
#define CB_PER_B (CBY * CBX)      // 150
#define NCB 600
#define OWS_HIST 0
#define OWS_OFFS 4096
#define OWS_CURS 8192
#define OWS_RECS 16384

#define SENTINEL 0xFFFFFFFFu

// ---------------------------------------------------------------------------
// Warp one event. Events sit on integer pixels -> flow bilinear gather
// degenerates to a direct lookup.
__device__ __forceinline__ void
warp_event(const float* __restrict__ flow, const float* __restrict__ ts,
           const int* __restrict__ ev_y, const int* __restrict__ ev_x,
           const int* __restrict__ pol, int i, int b,
           float& wy, float& wx, float& nts, int& p) {
    const int y = ev_y[i];
    const int x = ev_x[i];
    const float t = ts[i];
    p = pol[i];
    const float* fb = flow + (size_t)b * 2 * IMG_H * IMG_W;
    const int pix = y * IMG_W + x;
    const float fx = fb[pix];                  // ch0 = x-flow
    const float fy = fb[IMG_H * IMG_W + pix];  // ch1 = y-flow
    const float dt = 1.0f - t;                 // TREF - ts
    wy = (float)y + dt * fy;
    wx = (float)x + dt * fx;
    nts = 1.0f - fabsf(1.0f - t);
}

// ===========================================================================
// NEW PATH
// ===========================================================================

// Pass 1: per-block LDS-aggregated duplicate scatter.
//   Phase A: warp events, LDS-rank each record (primary in regs, rare
//            secondary-tile copies via LDS side list).
//   Phase B: one global cursor atomic per nonzero (block, tile), cursors
//            padded to 64B lines.
//   Phase C: write records into per-tile regions; overflow -> global spill.
__global__ void __launch_bounds__(256)
build_kernel(const float* __restrict__ flow, const float* __restrict__ ts,
             const int* __restrict__ ev_y, const int* __restrict__ ev_x,
             const int* __restrict__ pol,
             unsigned* __restrict__ curs, unsigned* __restrict__ spillcnt,
             float4* __restrict__ spill, float4* __restrict__ recs,
             int N, int cap) {
    __shared__ unsigned lh[OT_PER_B];      // per-local-tile record count
    __shared__ unsigned lbase[OT_PER_B];   // reserved global base per tile
    __shared__ unsigned side_cnt;
    __shared__ unsigned side_tile[SIDE_CAP];
    __shared__ unsigned side_rank[SIDE_CAP];
    __shared__ __align__(16) float4 side_rec[SIDE_CAP];

    const int tid = threadIdx.x;
    const int b = blockIdx.y;
    const int base = blockIdx.x * BD_CHUNK;

    for (int j = tid; j < OT_PER_B; j += 256) lh[j] = 0;
    if (tid == 0) side_cnt = 0;
    __syncthreads();

    float4 recK[BD_IPT];
    unsigned ltK[BD_IPT], rkK[BD_IPT];

    // Phase A
    #pragma unroll
    for (int k = 0; k < BD_IPT; ++k) {
        unsigned lt = 0xFFFFu, rank = 0;
        float4 rec;
        const int idx = base + k * 256 + tid;
        if (idx < N) {
            const int i = b * N + idx;
            float wy, wx, nts; int p;
            warp_event(flow, ts, ev_y, ev_x, pol, i, b, wy, wx, nts, p);
            const int iy0 = (int)floorf(wy);
            const int ix0 = (int)floorf(wx);
            int rys[2]; int nry = 0;
            if (iy0 >= 0 && iy0 < IMG_H) rys[nry++] = iy0 >> 4;
            if (iy0 + 1 >= 0 && iy0 + 1 < IMG_H) {
                const int r = (iy0 + 1) >> 4;
                if (nry == 0 || r != rys[0]) rys[nry++] = r;
            }
            int rxs[2]; int nrx = 0;
            if (ix0 >= 0 && ix0 < IMG_W) rxs[nrx++] = ix0 >> 5;
            if (ix0 + 1 >= 0 && ix0 + 1 < IMG_W) {
                const int r = (ix0 + 1) >> 5;
                if (nrx == 0 || r != rxs[0]) rxs[nrx++] = r;
            }
            if (nry > 0 && nrx > 0) {
                rec.x = wy; rec.y = wx; rec.z = nts;
                rec.w = __uint_as_float((unsigned)((b << 1) | (p & 1)));
                lt = (unsigned)(rys[0] * OTX + rxs[0]);
                rank = atomicAdd(&lh[lt], 1u);
                // rare secondary copies (straddling tile boundaries)
                const int ndup = nry * nrx;
                for (int d = 1; d < ndup; ++d) {
                    const int a = (nrx == 2) ? (d >> 1) : d;   // row sel
                    const int c = (nrx == 2) ? (d & 1) : 0;    // col sel
                    const unsigned lt2 = (unsigned)(rys[a] * OTX + rxs[c]);
                    const unsigned s = atomicAdd(&side_cnt, 1u);
                    if (s < SIDE_CAP) {
                        side_tile[s] = lt2;
                        side_rank[s] = atomicAdd(&lh[lt2], 1u);
                        side_rec[s] = rec;
                    } else {
                        const unsigned g = atomicAdd(spillcnt, 1u);
                        if (g < SPILL_CAP) spill[g] = rec;
                    }
                }
            }
        }
        recK[k] = rec; ltK[k] = lt; rkK[k] = rank;
    }
    __syncthreads();

    // Phase B: reserve per-tile global ranges (1 atomic per nonzero tile)
    for (int j = tid; j < OT_PER_B; j += 256) {
        const unsigned n = lh[j];
        lbase[j] = n ? atomicAdd(&curs[(size_t)(b * OT_PER_B + j) * CURS_STRIDE], n)
                     : 0u;
    }
    __syncthreads();

    // Phase C: write records
    #pragma unroll
    for (int k = 0; k < BD_IPT; ++k) {
        const unsigned lt = ltK[k];
        if (lt != 0xFFFFu) {
            const unsigned slot = lbase[lt] + rkK[k];
            if (slot < (unsigned)cap) {
                recs[(size_t)(b * OT_PER_B + lt) * cap + slot] = recK[k];
            } else {
                const unsigned g = atomicAdd(spillcnt, 1u);
                if (g < SPILL_CAP) spill[g] = recK[k];
            }
        }
    }
    const unsigned nside = min(side_cnt, (unsigned)SIDE_CAP);
    for (unsigned s = tid; s < nside; s += 256) {
        const unsigned lt = side_tile[s];
        const unsigned slot = lbase[lt] + side_rank[s];
        if (slot < (unsigned)cap) {
            recs[(size_t)(b * OT_PER_B + lt) * cap + slot] = side_rec[s];
        } else {
            const unsigned g = atomicAdd(spillcnt, 1u);
            if (g < SPILL_CAP) spill[g] = side_rec[s];
        }
    }
}

// Pass 2: one block per tile. Reads only its own records (1x redundancy,
// contiguous). LDS accumulate, plain float4 store-out (exclusive ownership).
__global__ void __launch_bounds__(256)
splat_own_kernel(const float4* __restrict__ recs, const unsigned* __restrict__ curs,
                 float* __restrict__ out, int cap) {
    __shared__ __align__(16) float acc[ACC_TOT];   // [4 planes][16][32]
    const int tile = blockIdx.x;
    const int tid = threadIdx.x;
    #pragma unroll
    for (int j = tid; j < ACC_TOT; j += 256) acc[j] = 0.0f;
    __syncthreads();

    const int b  = tile / OT_PER_B;
    const int rb = tile % OT_PER_B;
    const int sy = rb / OTX;
    const int sx = rb % OTX;

    const unsigned cnt = min(curs[(size_t)tile * CURS_STRIDE], (unsigned)cap);
    const float4* base = recs + (size_t)tile * cap;
    for (unsigned i = tid; i < cnt; i += 256) {
        const float4 r = base[i];
        const float wy = r.x, wx = r.y, nts = r.z;
        const int p = (int)(__float_as_uint(r.w) & 1u);
        const float byf = floorf(wy), bxf = floorf(wx);
        const int iy0 = (int)byf, ix0 = (int)bxf;
        const float ay = wy - byf, ax = wx - bxf;
        const float wyv[2] = {1.0f - ay, ay};
        const float wxv[2] = {1.0f - ax, ax};
        float* accc = acc + (p ? 0 : 1) * ACC_PLANE;  // count plane
        float* acct = accc + 2 * ACC_PLANE;           // ts plane
        #pragma unroll
        for (int dy = 0; dy < 2; ++dy) {
            const int gy = iy0 + dy;
            if ((gy >> 4) != sy) continue;            // rejects OOB too
            #pragma unroll
            for (int dx = 0; dx < 2; ++dx) {
                const int gx = ix0 + dx;
                if ((gx >> 5) != sx) continue;
                const float w = wyv[dy] * wxv[dx];
                const int idx = (gy & (OT_H - 1)) * OT_W + (gx & (OT_W - 1));
                atomicAdd(&accc[idx], w);
                atomicAdd(&acct[idx], w * nts);
            }
        }
    }
    __syncthreads();

    const int y0 = sy * OT_H;
    const int x0 = sx * OT_W;
    const float4* acc4 = (const float4*)acc;
    float* outb = out + (size_t)b * 4 * IMG_H * IMG_W;
    #pragma unroll
    for (int q = tid; q < ACC_TOT / 4; q += 256) {
        const int plane = q / (ACC_PLANE / 4);
        const int rem   = q % (ACC_PLANE / 4);
        const int ry    = rem / (OT_W / 4);
        const int rx4   = rem % (OT_W / 4);
        float4* dst = (float4*)(outb + (size_t)plane * IMG_H * IMG_W
                                + (size_t)(y0 + ry) * IMG_W + x0 + rx4 * 4);
        *dst = acc4[q];
    }
}

// Pass 3: apply spill records (normally zero) with global atomics, after splat.
__global__ void __launch_bounds__(256)
spill_kernel(const float4* __restrict__ spill, const unsigned* __restrict__ spillcnt,
             float* __restrict__ out) {
    const unsigned n = min(*spillcnt, (unsigned)SPILL_CAP);
    const unsigned stride = gridDim.x * 256;
    for (unsigned i = blockIdx.x * 256 + threadIdx.x; i < n; i += stride) {
        const float4 r = spill[i];
        const unsigned meta = __float_as_uint(r.w);
        const int p = (int)(meta & 1u);
        const int b = (int)(meta >> 1);
        const float wy = r.x, wx = r.y, nts = r.z;
        const float byf = floorf(wy), bxf = floorf(wx);
        const int iy0 = (int)byf, ix0 = (int)bxf;
        const float ay = wy - byf, ax = wx - bxf;
        const float wyv[2] = {1.0f - ay, ay};
        const float wxv[2] = {1.0f - ax, ax};
        float* out_c = out + ((size_t)b * 4 + (p ? 0 : 1)) * IMG_H * IMG_W;
        float* out_t = out_c + 2 * IMG_H * IMG_W;
        #pragma unroll
        for (int dy = 0; dy < 2; ++dy) {
            const int gy = iy0 + dy;
            if (gy < 0 || gy >= IMG_H) continue;
            #pragma unroll
            for (int dx = 0; dx < 2; ++dx) {
                const int gx = ix0 + dx;
                if (gx < 0 || gx >= IMG_W) continue;
                const float w = wyv[dy] * wxv[dx];
                const int o = gy * IMG_W + gx;
                atomicAdd(out_c + o, w);
                atomicAdd(out_t + o, w * nts);
            }
        }
    }
}

// ===========================================================================
// OLD PATH (round-3 pipeline, fallback when ws too small for the new layout)
// ===========================================================================
__device__ __forceinline__ unsigned
compute_tile(const float* __restrict__ flow, const float* __restrict__ ts,
             const int* __restrict__ ev_y, const int* __restrict__ ev_x,
             const int* __restrict__ pol, int i, int N,
             float& wy, float& wx, float& nts, int& p) {
    const int b = i / N;
    warp_event(flow, ts, ev_y, ev_x, pol, i, b, wy, wx, nts, p);
    const int iy0 = (int)floorf(wy);
    const int ix0 = (int)floorf(wx);
    if (iy0 < -1 || iy0 > IMG_H - 1 || ix0 < -1 || ix0 > IMG_W - 1)
        return SENTINEL;
    const int cy = min(max(iy0, 0), IMG_H - 1);
    const int cx = min(max(ix0, 0), IMG_W - 1);
    return (unsigned)((b * CBY + cy / CB_H) * CBX + cx / CB_W);
}

__global__ void __launch_bounds__(256)
hist_kernel(const float* __restrict__ flow, const float* __restrict__ ts,
            const int* __restrict__ ev_y, const int* __restrict__ ev_x,
            const int* __restrict__ pol,
            unsigned* __restrict__ hist, int N, int total) {
    __shared__ unsigned lh[NCB];
    const int tid = threadIdx.x;
    for (int j = tid; j < NCB; j += 256) lh[j] = 0;
    __syncthreads();
    const int stride = gridDim.x * 256;
    for (int i = blockIdx.x * 256 + tid; i < total; i += stride) {
        float wy, wx, nts; int p;
        unsigned t = compute_tile(flow, ts, ev_y, ev_x, pol, i, N, wy, wx, nts, p);
        if (t != SENTINEL) atomicAdd(&lh[t], 1u);
    }
    __syncthreads();
    for (int j = tid; j < NCB; j += 256) {
        unsigned n = lh[j];
        if (n) atomicAdd(&hist[j], n);
    }
}

__global__ void __launch_bounds__(1024)
scan_kernel(const unsigned* __restrict__ hist, unsigned* __restrict__ offs,
            unsigned* __restrict__ curs) {
    __shared__ unsigned s[1024];
    const int t = threadIdx.x;
    s[t] = (t < NCB) ? hist[t] : 0u;
    __syncthreads();
    #pragma unroll
    for (int d = 1; d < 1024; d <<= 1) {
        unsigned v = (t >= d) ? s[t - d] : 0u;
        __syncthreads();
        s[t] += v;
        __syncthreads();
    }
    if (t < NCB) {
        unsigned excl = (t == 0) ? 0u : s[t - 1];
        offs[t] = excl;
        curs[t] = excl;
        if (t == NCB - 1) offs[NCB] = s[t];
    }
}

#define SC_IPT 8
#define SC_CHUNK (256 * SC_IPT)
__global__ void __launch_bounds__(256)
scatter_kernel(const float* __restrict__ flow, const float* __restrict__ ts,
               const int* __restrict__ ev_y, const int* __restrict__ ev_x,
               const int* __restrict__ pol,
               unsigned* __restrict__ curs, float4* __restrict__ recs,
               int N, int total) {
    __shared__ unsigned lhist[NCB];
    __shared__ unsigned lbase[NCB];
    const int tid = threadIdx.x;
    for (int j = tid; j < NCB; j += 256) lhist[j] = 0;
    __syncthreads();
    const int base_i = blockIdx.x * SC_CHUNK;
    unsigned tK[SC_IPT], rkK[SC_IPT];
    float wyK[SC_IPT], wxK[SC_IPT], ntsK[SC_IPT];
    int pK[SC_IPT];
    #pragma unroll
    for (int k = 0; k < SC_IPT; ++k) {
        const int i = base_i + k * 256 + tid;
        unsigned t = SENTINEL;
        if (i < total)
            t = compute_tile(flow, ts, ev_y, ev_x, pol, i, N,
                             wyK[k], wxK[k], ntsK[k], pK[k]);
        tK[k] = t;
        if (t != SENTINEL) rkK[k] = atomicAdd(&lhist[t], 1u);
    }
    __syncthreads();
    for (int j = tid; j < NCB; j += 256) {
        unsigned n = lhist[j];
        lbase[j] = n ? atomicAdd(&curs[j], n) : 0u;
    }
    __syncthreads();
    #pragma unroll
    for (int k = 0; k < SC_IPT; ++k) {
        const unsigned t = tK[k];
        if (t != SENTINEL) {
            float4 r;
            r.x = wyK[k]; r.y = wxK[k]; r.z = ntsK[k];
            r.w = __uint_as_float((unsigned)(pK[k] & 1));
            recs[lbase[t] + rkK[k]] = r;
        }
    }
}

__global__ void __launch_bounds__(256)
splat_cb_kernel(const float4* __restrict__ recs, const unsigned* __restrict__ offs,
                float* __restrict__ out) {
    __shared__ __align__(16) float acc[ACC_TOT];
    const int tile = blockIdx.x;
    const int tid = threadIdx.x;
    #pragma unroll
    for (int j = tid; j < ACC_TOT; j += 256) acc[j] = 0.0f;
    __syncthreads();
    const int b  = tile / OT_PER_B;
    const int rb = tile % OT_PER_B;
    const int sy = rb / OTX;
    const int sx = rb % OTX;
    const int ty_hi = sy >> 1, tx_hi = sx >> 1;
    const int ty_lo = ((sy & 1) == 0 && ty_hi > 0) ? ty_hi - 1 : ty_hi;
    const int tx_lo = ((sx & 1) == 0 && tx_hi > 0) ? tx_hi - 1 : tx_hi;
    for (int ty = ty_lo; ty <= ty_hi; ++ty) {
        const unsigned start = offs[(b * CBY + ty) * CBX + tx_lo];
        const unsigned end   = offs[(b * CBY + ty) * CBX + tx_hi + 1];
        for (unsigned i = start + tid; i < end; i += 256) {
            const float4 r = recs[i];
            const float wy = r.x, wx = r.y, nts = r.z;
            const int p = (int)(__float_as_uint(r.w) & 1u);
            const float byf = floorf(wy), bxf = floorf(wx);
            const int iy0 = (int)byf, ix0 = (int)bxf;
            const float ay = wy - byf, ax = wx - bxf;
            const float wyv[2] = {1.0f - ay, ay};
            const float wxv[2] = {1.0f - ax, ax};
            float* accc = acc + (p ? 0 : 1) * ACC_PLANE;
            float* acct = accc + 2 * ACC_PLANE;
            #pragma unroll
            for (int dy = 0; dy < 2; ++dy) {
                const int gy = iy0 + dy;
                if ((gy >> 4) != sy) continue;
                #pragma unroll
                for (int dx = 0; dx < 2; ++dx) {
                    const int gx = ix0 + dx;
                    if ((gx >> 5) != sx) continue;
                    const float w = wyv[dy] * wxv[dx];
                    const int idx = (gy & (OT_H - 1)) * OT_W + (gx & (OT_W - 1));
                    atomicAdd(&accc[idx], w);
                    atomicAdd(&acct[idx], w * nts);
                }
            }
        }
    }
    __syncthreads();
    const int y0 = sy * OT_H, x0 = sx * OT_W;
    const float4* acc4 = (const float4*)acc;
    float* outb = out + (size_t)b * 4 * IMG_H * IMG_W;
    #pragma unroll
    for (int q = tid; q < ACC_TOT / 4; q += 256) {
        const int plane = q / (ACC_PLANE / 4);
        const int rem   = q % (ACC_PLANE / 4);
        const int ry    = rem / (OT_W / 4);
        const int rx4   = rem % (OT_W / 4);
        float4* dst = (float4*)(outb + (size_t)plane * IMG_H * IMG_W
                                + (size_t)(y0 + ry) * IMG_W + x0 + rx4 * 4);
        *dst = acc4[q];
    }
}

// Last-resort fallback: direct global atomics (needs zeroed out).
__global__ void __launch_bounds__(256)
event_splat_fallback(const float* __restrict__ flow, const float* __restrict__ ts,
                     const int* __restrict__ ev_y, const int* __restrict__ ev_x,
                     const int* __restrict__ pol, float* __restrict__ out,
                     int N, int total) {
    const int i = blockIdx.x * blockDim.x + threadIdx.x;
    if (i >= total) return;
    float wy, wx, nts; int p;
    unsigned t = compute_tile(flow, ts, ev_y, ev_x, pol, i, N, wy, wx, nts, p);
    if (t == SENTINEL) return;
    const int b = i / N;
    const float byf = floorf(wy), bxf = floorf(wx);
    const int iy0 = (int)byf, ix0 = (int)bxf;
    const float ay = wy - byf, ax = wx - bxf;
    const float wyv[2] = {1.0f - ay, ay};
    const float wxv[2] = {1.0f - ax, ax};
    float* out_c = out + ((size_t)b * 4 + (p ? 0 : 1)) * IMG_H * IMG_W;
    float* out_t = out_c + 2 * IMG_H * IMG_W;
    #pragma unroll
    for (int dy = 0; dy < 2; ++dy) {
        const int gy = iy0 + dy;
        if (gy < 0 || gy >= IMG_H) continue;
        #pragma unroll
        for (int dx = 0; dx < 2; ++dx) {
            const int gx = ix0 + dx;
            if (gx < 0 || gx >= IMG_W) continue;
            const float w = wyv[dy] * wxv[dx];
            const int o = gy * IMG_W + gx;
            atomicAdd(out_c + o, w);
            atomicAdd(out_t + o, w * nts);
        }
    }
}

// ---------------------------------------------------------------------------
extern "C" void kernel_launch(void* const* d_in, const int* in_sizes, int n_in,
                              void* d_out, int out_size, void* d_ws, size_t ws_size,
                              hipStream_t stream) {
    const float* flow = (const float*)d_in[0];
    const float* ts   = (const float*)d_in[1];
    const int*   ev_y = (const int*)d_in[2];
    const int*   ev_x = (const int*)d_in[3];
    const int*   pol  = (const int*)d_in[4];
    float* out = (float*)d_out;

    const int total = in_sizes[2];                  // B*N
    const int B = out_size / (4 * IMG_H * IMG_W);
    const int N = total / B;
    char* ws = (char*)d_ws;

    // --- NEW path: needs WS_RECS + NT*cap*16 bytes; cap >= 704 keeps
    //     per-tile overflow probability ~0 (mean 548, sigma ~23.5).
    int cap = 0;
    if (ws_size > (size_t)WS_RECS)
        cap = (int)((ws_size - WS_RECS) / ((size_t)NT * sizeof(float4)));
    if (cap > 2048) cap = 2048;
    cap &= ~3;

    if (B == NB && cap >= 704) {
        unsigned* curs     = (unsigned*)(ws + WS_CURS);
        unsigned* spillcnt = (unsigned*)(ws + WS_SPILLCNT);
        float4*   spill    = (float4*)(ws + WS_SPILL);
        float4*   recs     = (float4*)(ws + WS_RECS);

        // zero padded cursor region + spillcnt in one go
        hipMemsetAsync(ws, 0, WS_SPILL, stream);

        dim3 bgrid((N + BD_CHUNK - 1) / BD_CHUNK, B);
        build_kernel<<<bgrid, 256, 0, stream>>>(flow, ts, ev_y, ev_x, pol,
                                                curs, spillcnt, spill, recs,
                                                N, cap);
        splat_own_kernel<<<NT, 256, 0, stream>>>(recs, curs, out, cap);
        spill_kernel<<<16, 256, 0, stream>>>(spill, spillcnt, out);
        return;
    }

    // --- OLD path (round-3 pipeline)
    const size_t ws_needed_old = (size_t)OWS_RECS + (size_t)total * sizeof(float4);
    if (B * CB_PER_B == NCB && ws_size >= ws_needed_old) {
        unsigned* hist = (unsigned*)(ws + OWS_HIST);
        unsigned* offs = (unsigned*)(ws + OWS_OFFS);
        unsigned* curs = (unsigned*)(ws + OWS_CURS);
        float4*   recs = (float4*)(ws + OWS_RECS);

        hipMemsetAsync(hist, 0, NCB * sizeof(unsigned), stream);
        hist_kernel<<<300, 256, 0, stream>>>(flow, ts, ev_y, ev_x, pol, hist, N, total);
        scan_kernel<<<1, 1024, 0, stream>>>(hist, offs, curs);
        const int sc_blocks = (total + SC_CHUNK - 1) / SC_CHUNK;
        scatter_kernel<<<sc_blocks, 256, 0, stream>>>(flow, ts, ev_y, ev_x, pol,
                                                      curs, recs, N, total);
        splat_cb_kernel<<<B * OT_PER_B, 256, 0, stream>>>(recs, offs, out);
        return;
    }

    // --- last resort
    hipMemsetAsync(d_out, 0, (size_t)out_size * sizeof(float), stream);
    const int blocks = (total + 255) / 256;
    event_splat_fallback<<<blocks, 256, 0, stream>>>(flow, ts, ev_y, ev_x, pol,
                                                     out, N, total);
}

// Round 6
// 184.098 us; speedup vs baseline: 2.1030x; 1.0300x over previous
//
#include <hip/hip_runtime.h>

// Event-warp + bilinear splat, v6: source-tile counting sort (keys need NO
// flow gather) -> per-source-tile build with L1-local flow gather + 3x3-ring
// dest scatter (8-B quantized records) -> 1x-read ownership-tile splat with
// atomic-free writeout.
// Inputs (setup_inputs order):
//   d_in[0] flow  : float32 [B,2,H,W]   (ch0 = x-flow, ch1 = y-flow)
//   d_in[1] ts    : float32 [B,N,1]
//   d_in[2] ev_y  : int32   [B,N]
//   d_in[3] ev_x  : int32   [B,N]
//   d_in[4] pol   : int32   [B,N]  (1 = positive, 0 = negative)
// Output: float32 [B,4,H,W] = (iwe_pos, iwe_neg, iwe_pos_ts, iwe_neg_ts)

#define IMG_H 480
#define IMG_W 640

// Ownership tiles: 16x32 (both source-sort key and splat granularity)
#define OT_H 16
#define OT_W 32
#define OTY (IMG_H / OT_H)        // 30
#define OTX (IMG_W / OT_W)        // 20
#define OT_PER_B (OTY * OTX)      // 600
#define NB 4                      // expected batch
#define NT (NB * OT_PER_B)        // 2400

#define ACC_PLANE (OT_H * OT_W)   // 512 floats
#define ACC_TOT (4 * ACC_PLANE)   // 2048 floats = 8 KB LDS

// ws layout (byte offsets)
#define SCURS_STRIDE 16                 // u32 stride -> 64 B padded lines
#define WS_SCURS 0                      // NT * 64 B            = 153600
#define WS_DCURS 153600                 // NT * 4 B             = 9600
#define WS_SPILLCNT 163200              // 4 B
#define WS_SPILL 163840                 // SPILL_CAP * 16 B     = 512 KB
#define SPILL_CAP 32768
#define WS_RECS 688128                  // srecs (NT*cap*8) then drecs (NT*cap*8)

#define K1_IPT 8
#define K1_CHUNK (256 * K1_IPT)         // 2048 events per block

// ---------------------------------------------------------------------------
__device__ __forceinline__ void
warp_from(const float* __restrict__ flow, int b, int y, int x, float t,
          float& wy, float& wx, float& nts) {
    const float* fb = flow + (size_t)b * 2 * IMG_H * IMG_W;
    const int pix = y * IMG_W + x;
    const float fx = fb[pix];                  // ch0 = x-flow
    const float fy = fb[IMG_H * IMG_W + pix];  // ch1 = y-flow
    const float dt = 1.0f - t;                 // TREF - ts
    wy = (float)y + dt * fy;
    wx = (float)x + dt * fx;
    nts = 1.0f - fabsf(1.0f - t);
}

// ---------------------------------------------------------------------------
// K1: counting-scatter by SOURCE tile. Key from ev_y/ev_x directly (no flow
// read). LDS-rank per block, one padded-cursor atomic per nonzero (block,tile).
// Overflow events (cap exceeded, ~never) are fully processed inline -> spill.
__global__ void __launch_bounds__(256)
ssort_kernel(const float* __restrict__ flow, const float* __restrict__ ts,
             const int* __restrict__ ev_y, const int* __restrict__ ev_x,
             const int* __restrict__ pol,
             unsigned* __restrict__ scurs, unsigned* __restrict__ spillcnt,
             float4* __restrict__ spill, uint2* __restrict__ srecs,
             int N, int cap) {
    __shared__ unsigned lh[OT_PER_B];
    __shared__ unsigned lbase[OT_PER_B];
    const int tid = threadIdx.x;
    const int b = blockIdx.y;
    const int base = blockIdx.x * K1_CHUNK;

    for (int j = tid; j < OT_PER_B; j += 256) lh[j] = 0;
    __syncthreads();

    unsigned mK[K1_IPT], ltK[K1_IPT], rkK[K1_IPT];
    float tsK[K1_IPT];

    #pragma unroll
    for (int k = 0; k < K1_IPT; ++k) {
        const int idx = base + k * 256 + tid;
        unsigned lt = 0xFFFFu, rk = 0, m = 0; float t = 0.f;
        if (idx < N) {
            const int i = b * N + idx;
            const int y = ev_y[i];
            const int x = ev_x[i];
            t = ts[i];
            const int p = pol[i];
            lt = (unsigned)((y >> 4) * OTX + (x >> 5));
            rk = atomicAdd(&lh[lt], 1u);
            m = (unsigned)y | ((unsigned)x << 9) | ((unsigned)(p & 1) << 19);
        }
        mK[k] = m; ltK[k] = lt; rkK[k] = rk; tsK[k] = t;
    }
    __syncthreads();

    for (int j = tid; j < OT_PER_B; j += 256) {
        const unsigned n = lh[j];
        lbase[j] = n ? atomicAdd(&scurs[(size_t)(b * OT_PER_B + j) * SCURS_STRIDE], n)
                     : 0u;
    }
    __syncthreads();

    #pragma unroll
    for (int k = 0; k < K1_IPT; ++k) {
        const unsigned lt = ltK[k];
        if (lt == 0xFFFFu) continue;
        const unsigned slot = lbase[lt] + rkK[k];
        if (slot < (unsigned)cap) {
            uint2 r; r.x = mK[k]; r.y = __float_as_uint(tsK[k]);
            srecs[(size_t)(b * OT_PER_B + lt) * cap + slot] = r;
        } else {
            // rare: process fully now, defer application via spill list
            const int y = (int)(mK[k] & 511u);
            const int x = (int)((mK[k] >> 9) & 1023u);
            const int p = (int)((mK[k] >> 19) & 1u);
            float wy, wx, nts;
            warp_from(flow, b, y, x, tsK[k], wy, wx, nts);
            const unsigned g = atomicAdd(spillcnt, 1u);
            if (g < SPILL_CAP) {
                float4 s; s.x = wy; s.y = wx; s.z = nts;
                s.w = __uint_as_float((unsigned)((b << 1) | p));
                spill[g] = s;
            }
        }
    }
}

// ---------------------------------------------------------------------------
// K2: one block per source tile (~500 contiguous records). Flow gather is
// L1-local (4 KB footprint/block). Dest tiles confined to the 3x3 ring
// (|disp| <= 15/31 px at >=7 sigma); LDS-rank on 9 counters, 9 global cursor
// atomics per block. Dest records quantized to 8 B, tile-relative.
__global__ void __launch_bounds__(256)
build2_kernel(const float* __restrict__ flow,
              const unsigned* __restrict__ scurs, unsigned* __restrict__ dcurs,
              unsigned* __restrict__ spillcnt, float4* __restrict__ spill,
              const uint2* __restrict__ srecs, uint2* __restrict__ drecs,
              int cap) {
    __shared__ unsigned dh[9];
    __shared__ unsigned dbase[9];
    const int tile = blockIdx.x;
    const int tid = threadIdx.x;
    const int b   = tile / OT_PER_B;
    const int lt  = tile % OT_PER_B;
    const int ssy = lt / OTX;
    const int ssx = lt % OTX;

    if (tid < 9) dh[tid] = 0;
    __syncthreads();

    const unsigned cnt = min(scurs[(size_t)tile * SCURS_STRIDE], (unsigned)cap);
    const uint2* sbase = srecs + (size_t)tile * cap;

    // cap <= 1024 -> 4 iterations cover everything
    float wyK[4], wxK[4], ntsK[4];
    unsigned pK[4], ndK[4], relK[4], rk0K[4], rk1K[4], rk2K[4], rk3K[4];

    #pragma unroll
    for (int k = 0; k < 4; ++k) {
        unsigned nd = 0, relp = 0;
        unsigned r0 = 0, r1 = 0, r2 = 0, r3 = 0;
        float wy = 0.f, wx = 0.f, nts = 0.f; unsigned p = 0;
        const unsigned i = (unsigned)(k * 256 + tid);
        if (i < cnt) {
            const uint2 sr = sbase[i];
            const int y = (int)(sr.x & 511u);
            const int x = (int)((sr.x >> 9) & 1023u);
            p = (sr.x >> 19) & 1u;
            const float t = __uint_as_float(sr.y);
            warp_from(flow, b, y, x, t, wy, wx, nts);

            const int iy0 = (int)floorf(wy);
            const int ix0 = (int)floorf(wx);
            int rys[2]; int nry = 0;
            if (iy0 >= 0 && iy0 < IMG_H) rys[nry++] = iy0 >> 4;
            if (iy0 + 1 >= 0 && iy0 + 1 < IMG_H) {
                const int r = (iy0 + 1) >> 4;
                if (nry == 0 || r != rys[0]) rys[nry++] = r;
            }
            int rxs[2]; int nrx = 0;
            if (ix0 >= 0 && ix0 < IMG_W) rxs[nrx++] = ix0 >> 5;
            if (ix0 + 1 >= 0 && ix0 + 1 < IMG_W) {
                const int r = (ix0 + 1) >> 5;
                if (nrx == 0 || r != rxs[0]) rxs[nrx++] = r;
            }
            if (nry > 0 && nrx > 0) {
                bool oob = false;
                unsigned rels[4]; unsigned m = 0;
                for (int a = 0; a < nry; ++a)
                    for (int c = 0; c < nrx; ++c) {
                        const int ry_r = rys[a] - ssy + 1;
                        const int rx_r = rxs[c] - ssx + 1;
                        if ((unsigned)ry_r > 2u || (unsigned)rx_r > 2u) oob = true;
                        else rels[m++] = (unsigned)(ry_r * 3 + rx_r);
                    }
                if (oob) {
                    // whole event via spill (all 4 corners applied there once)
                    const unsigned g = atomicAdd(spillcnt, 1u);
                    if (g < SPILL_CAP) {
                        float4 s; s.x = wy; s.y = wx; s.z = nts;
                        s.w = __uint_as_float((unsigned)((b << 1) | p));
                        spill[g] = s;
                    }
                } else {
                    nd = m;
                    for (unsigned d = 0; d < m; ++d) {
                        relp |= rels[d] << (8 * d);
                        const unsigned rr = atomicAdd(&dh[rels[d]], 1u);
                        if (d == 0) r0 = rr; else if (d == 1) r1 = rr;
                        else if (d == 2) r2 = rr; else r3 = rr;
                    }
                }
            }
        }
        wyK[k] = wy; wxK[k] = wx; ntsK[k] = nts; pK[k] = p;
        ndK[k] = nd; relK[k] = relp;
        rk0K[k] = r0; rk1K[k] = r1; rk2K[k] = r2; rk3K[k] = r3;
    }
    __syncthreads();

    if (tid < 9) {
        const unsigned n = dh[tid];
        if (n) {
            const int dty = ssy + tid / 3 - 1;
            const int dtx = ssx + tid % 3 - 1;
            dbase[tid] = atomicAdd(&dcurs[b * OT_PER_B + dty * OTX + dtx], n);
        }
    }
    __syncthreads();

    #pragma unroll
    for (int k = 0; k < 4; ++k) {
        const unsigned nd = ndK[k];
        for (unsigned d = 0; d < nd; ++d) {
            const unsigned rel = (relK[k] >> (8 * d)) & 0xFFu;
            const unsigned rr = (d == 0) ? rk0K[k] : (d == 1) ? rk1K[k]
                              : (d == 2) ? rk2K[k] : rk3K[k];
            const int dty = ssy + (int)(rel / 3) - 1;
            const int dtx = ssx + (int)(rel % 3) - 1;
            const unsigned slot = dbase[rel] + rr;
            if (slot < (unsigned)cap) {
                int qy = __float2int_rn((wyK[k] - 16.0f * dty + 1.0f) * 2048.0f);
                int qx = __float2int_rn((wxK[k] - 32.0f * dtx + 1.0f) * 1024.0f);
                int qt = __float2int_rn(ntsK[k] * 32767.0f);
                qy = min(max(qy, 0), 65535);
                qx = min(max(qx, 0), 65535);
                qt = min(max(qt, 0), 32767);
                uint2 dr;
                dr.x = (unsigned)qy | ((unsigned)qx << 16);
                dr.y = (unsigned)qt | (pK[k] << 15);
                drecs[(size_t)(b * OT_PER_B + dty * OTX + dtx) * cap + slot] = dr;
            } else {
                const unsigned g = atomicAdd(spillcnt, 1u);
                if (g < SPILL_CAP) {
                    float4 s; s.x = wyK[k]; s.y = wxK[k]; s.z = ntsK[k];
                    s.w = __uint_as_float((unsigned)((b << 1) | pK[k]));
                    spill[g] = s;
                    break;   // spill covers ALL corners: skip remaining dests
                }
            }
        }
    }
}

// ---------------------------------------------------------------------------
// K3: one block per ownership tile. Decode 8-B local records, LDS accumulate,
// plain float4 store-out (exclusive ownership -> no out-memset needed).
__global__ void __launch_bounds__(256)
splat_kernel(const uint2* __restrict__ drecs, const unsigned* __restrict__ dcurs,
             float* __restrict__ out, int cap) {
    __shared__ __align__(16) float acc[ACC_TOT];   // [4 planes][16][32]
    const int tile = blockIdx.x;
    const int tid = threadIdx.x;
    #pragma unroll
    for (int j = tid; j < ACC_TOT; j += 256) acc[j] = 0.0f;
    __syncthreads();

    const unsigned cnt = min(dcurs[tile], (unsigned)cap);
    const uint2* base = drecs + (size_t)tile * cap;
    for (unsigned i = tid; i < cnt; i += 256) {
        const uint2 r = base[i];
        const float ry  = (float)(r.x & 0xFFFFu) * (1.0f / 2048.0f) - 1.0f;
        const float rx  = (float)(r.x >> 16)     * (1.0f / 1024.0f) - 1.0f;
        const float nts = (float)(r.y & 0x7FFFu) * (1.0f / 32767.0f);
        const int p = (int)((r.y >> 15) & 1u);
        const float byf = floorf(ry), bxf = floorf(rx);
        const int iy0 = (int)byf, ix0 = (int)bxf;      // in [-1, 16] / [-1, 32]
        const float ay = ry - byf, ax = rx - bxf;
        const float wyv[2] = {1.0f - ay, ay};
        const float wxv[2] = {1.0f - ax, ax};
        float* accc = acc + (p ? 0 : 1) * ACC_PLANE;   // count plane
        float* acct = accc + 2 * ACC_PLANE;            // ts plane
        #pragma unroll
        for (int dy = 0; dy < 2; ++dy) {
            const int gy = iy0 + dy;
            if ((unsigned)gy >= (unsigned)OT_H) continue;
            #pragma unroll
            for (int dx = 0; dx < 2; ++dx) {
                const int gx = ix0 + dx;
                if ((unsigned)gx >= (unsigned)OT_W) continue;
                const float w = wyv[dy] * wxv[dx];
                const int idx = gy * OT_W + gx;
                atomicAdd(&accc[idx], w);
                atomicAdd(&acct[idx], w * nts);
            }
        }
    }
    __syncthreads();

    const int b  = tile / OT_PER_B;
    const int rb = tile % OT_PER_B;
    const int y0 = (rb / OTX) * OT_H;
    const int x0 = (rb % OTX) * OT_W;
    const float4* acc4 = (const float4*)acc;
    float* outb = out + (size_t)b * 4 * IMG_H * IMG_W;
    #pragma unroll
    for (int q = tid; q < ACC_TOT / 4; q += 256) {
        const int plane = q / (ACC_PLANE / 4);
        const int rem   = q % (ACC_PLANE / 4);
        const int ry    = rem / (OT_W / 4);
        const int rx4   = rem % (OT_W / 4);
        float4* dst = (float4*)(outb + (size_t)plane * IMG_H * IMG_W
                                + (size_t)(y0 + ry) * IMG_W + x0 + rx4 * 4);
        *dst = acc4[q];
    }
}

// ---------------------------------------------------------------------------
// K4: apply spill records (normally zero) with global atomics, after splat.
__global__ void __launch_bounds__(256)
spill_kernel(const float4* __restrict__ spill, const unsigned* __restrict__ spillcnt,
             float* __restrict__ out) {
    const unsigned n = min(*spillcnt, (unsigned)SPILL_CAP);
    const unsigned stride = gridDim.x * 256;
    for (unsigned i = blockIdx.x * 256 + threadIdx.x; i < n; i += stride) {
        const float4 r = spill[i];
        const unsigned meta = __float_as_uint(r.w);
        const int p = (int)(meta & 1u);
        const int b = (int)(meta >> 1);
        const float wy = r.x, wx = r.y, nts = r.z;
        const float byf = floorf(wy), bxf = floorf(wx);
        const int iy0 = (int)byf, ix0 = (int)bxf;
        const float ay = wy - byf, ax = wx - bxf;
        const float wyv[2] = {1.0f - ay, ay};
        const float wxv[2] = {1.0f - ax, ax};
        float* out_c = out + ((size_t)b * 4 + (p ? 0 : 1)) * IMG_H * IMG_W;
        float* out_t = out_c + 2 * IMG_H * IMG_W;
        #pragma unroll
        for (int dy = 0; dy < 2; ++dy) {
            const int gy = iy0 + dy;
            if (gy < 0 || gy >= IMG_H) continue;
            #pragma unroll
            for (int dx = 0; dx < 2; ++dx) {
                const int gx = ix0 + dx;
                if (gx < 0 || gx >= IMG_W) continue;
                const float w = wyv[dy] * wxv[dx];
                const int o = gy * IMG_W + gx;
                atomicAdd(out_c + o, w);
                atomicAdd(out_t + o, w * nts);
            }
        }
    }
}

// ---------------------------------------------------------------------------
// Last-resort fallback: direct global atomics (needs zeroed out).
__global__ void __launch_bounds__(256)
event_splat_fallback(const float* __restrict__ flow, const float* __restrict__ ts,
                     const int* __restrict__ ev_y, const int* __restrict__ ev_x,
                     const int* __restrict__ pol, float* __restrict__ out,
                     int N, int total) {
    const int i = blockIdx.x * blockDim.x + threadIdx.x;
    if (i >= total) return;
    const int b = i / N;
    float wy, wx, nts;
    warp_from(flow, b, ev_y[i], ev_x[i], ts[i], wy, wx, nts);
    const int p = pol[i];
    const float byf = floorf(wy), bxf = floorf(wx);
    const int iy0 = (int)byf, ix0 = (int)bxf;
    const float ay = wy - byf, ax = wx - bxf;
    const float wyv[2] = {1.0f - ay, ay};
    const float wxv[2] = {1.0f - ax, ax};
    float* out_c = out + ((size_t)b * 4 + (p ? 0 : 1)) * IMG_H * IMG_W;
    float* out_t = out_c + 2 * IMG_H * IMG_W;
    #pragma unroll
    for (int dy = 0; dy < 2; ++dy) {
        const int gy = iy0 + dy;
        if (gy < 0 || gy >= IMG_H) continue;
        #pragma unroll
        for (int dx = 0; dx < 2; ++dx) {
            const int gx = ix0 + dx;
            if (gx < 0 || gx >= IMG_W) continue;
            const float w = wyv[dy] * wxv[dx];
            const int o = gy * IMG_W + gx;
            atomicAdd(out_c + o, w);
            atomicAdd(out_t + o, w * nts);
        }
    }
}

// ---------------------------------------------------------------------------
extern "C" void kernel_launch(void* const* d_in, const int* in_sizes, int n_in,
                              void* d_out, int out_size, void* d_ws, size_t ws_size,
                              hipStream_t stream) {
    const float* flow = (const float*)d_in[0];
    const float* ts   = (const float*)d_in[1];
    const int*   ev_y = (const int*)d_in[2];
    const int*   ev_x = (const int*)d_in[3];
    const int*   pol  = (const int*)d_in[4];
    float* out = (float*)d_out;

    const int total = in_sizes[2];                  // B*N
    const int B = out_size / (4 * IMG_H * IMG_W);
    const int N = total / B;
    char* ws = (char*)d_ws;

    // cap slots per tile for srec (8 B) + drec (8 B): 16 B/slot/tile.
    // cap >= 640 covers mean 500/548 at >= +4.8 sigma; overflow -> spill.
    int cap = 0;
    if (ws_size > (size_t)WS_RECS)
        cap = (int)((ws_size - WS_RECS) / ((size_t)NT * 16));
    if (cap > 1024) cap = 1024;
    cap &= ~3;

    if (B == NB && cap >= 640) {
        unsigned* scurs    = (unsigned*)(ws + WS_SCURS);
        unsigned* dcurs    = (unsigned*)(ws + WS_DCURS);
        unsigned* spillcnt = (unsigned*)(ws + WS_SPILLCNT);
        float4*   spill    = (float4*)(ws + WS_SPILL);
        uint2*    srecs    = (uint2*)(ws + WS_RECS);
        uint2*    drecs    = (uint2*)(ws + WS_RECS + (size_t)NT * cap * 8);

        hipMemsetAsync(ws, 0, WS_SPILL, stream);    // scurs + dcurs + spillcnt

        dim3 g1((N + K1_CHUNK - 1) / K1_CHUNK, NB);
        ssort_kernel<<<g1, 256, 0, stream>>>(flow, ts, ev_y, ev_x, pol,
                                             scurs, spillcnt, spill, srecs,
                                             N, cap);
        build2_kernel<<<NT, 256, 0, stream>>>(flow, scurs, dcurs, spillcnt,
                                              spill, srecs, drecs, cap);
        splat_kernel<<<NT, 256, 0, stream>>>(drecs, dcurs, out, cap);
        spill_kernel<<<16, 256, 0, stream>>>(spill, spillcnt, out);
        return;
    }

    // last resort
    hipMemsetAsync(d_out, 0, (size_t)out_size * sizeof(float), stream);
    const int blocks = (total + 255) / 256;
    event_splat_fallback<<<blocks, 256, 0, stream>>>(flow, ts, ev_y, ev_x, pol,
                                                     out, N, total);
}

// Round 7
// 144.504 us; speedup vs baseline: 2.6793x; 1.2740x over previous
//
#include <hip/hip_runtime.h>

// Event-warp + bilinear splat, v7.
//   K1 ssort : source-tile counting scatter (no flow read), 512-thr blocks,
//              IPT=2 -> ~32 waves/CU (was 9).
//   K2 build2: 2 blocks per source tile (4800 blocks), flow tile preloaded
//              into LDS, 3x3-ring dest scatter, 8-B quantized records.
//   K3 splat : 1x-read ownership-tile splat; (w, w*nts) packed into ONE
//              ds_add_u64 (Q20 fixed point) -> half the LDS atomics;
//              spill application fused in; pure float4 writeout.
// Inputs (setup_inputs order):
//   d_in[0] flow  : float32 [B,2,H,W]   (ch0 = x-flow, ch1 = y-flow)
//   d_in[1] ts    : float32 [B,N,1]
//   d_in[2] ev_y  : int32   [B,N]
//   d_in[3] ev_x  : int32   [B,N]
//   d_in[4] pol   : int32   [B,N]  (1 = positive, 0 = negative)
// Output: float32 [B,4,H,W] = (iwe_pos, iwe_neg, iwe_pos_ts, iwe_neg_ts)

#define IMG_H 480
#define IMG_W 640

#define OT_H 16
#define OT_W 32
#define OTY (IMG_H / OT_H)        // 30
#define OTX (IMG_W / OT_W)        // 20
#define OT_PER_B (OTY * OTX)      // 600
#define NB 4
#define NT (NB * OT_PER_B)        // 2400

#define ACC_PLANE (OT_H * OT_W)   // 512 cells

// ws layout (byte offsets)
#define SCURS_STRIDE 16                 // u32 stride -> 64 B padded lines
#define WS_SCURS 0                      // NT * 64 B = 153600
#define WS_DCURS 153600                 // NT * 4 B  = 9600
#define WS_SPILLCNT 163200              // 4 B
#define WS_SPILL 163840                 // SPILL_CAP * 16 B = 512 KB
#define SPILL_CAP 32768
#define WS_RECS 688128                  // srecs (NT*cap*8) then drecs (NT*cap*8)

#define SSORT_THREADS 512
#define K1_IPT 2
#define K1_CHUNK (SSORT_THREADS * K1_IPT)   // 1024 events per block

#define Q20 1048576.0f
#define INV_Q20 9.5367431640625e-07f

// ---------------------------------------------------------------------------
__device__ __forceinline__ void
warp_from(const float* __restrict__ flow, int b, int y, int x, float t,
          float& wy, float& wx, float& nts) {
    const float* fb = flow + (size_t)b * 2 * IMG_H * IMG_W;
    const int pix = y * IMG_W + x;
    const float fx = fb[pix];
    const float fy = fb[IMG_H * IMG_W + pix];
    const float dt = 1.0f - t;
    wy = (float)y + dt * fy;
    wx = (float)x + dt * fx;
    nts = 1.0f - fabsf(1.0f - t);
}

// ---------------------------------------------------------------------------
// K1: counting-scatter by SOURCE tile (key from ev_y/ev_x directly).
__global__ void __launch_bounds__(SSORT_THREADS)
ssort_kernel(const float* __restrict__ flow, const float* __restrict__ ts,
             const int* __restrict__ ev_y, const int* __restrict__ ev_x,
             const int* __restrict__ pol,
             unsigned* __restrict__ scurs, unsigned* __restrict__ spillcnt,
             float4* __restrict__ spill, uint2* __restrict__ srecs,
             int N, int cap) {
    __shared__ unsigned lh[OT_PER_B];
    __shared__ unsigned lbase[OT_PER_B];
    const int tid = threadIdx.x;
    const int b = blockIdx.y;
    const int base = blockIdx.x * K1_CHUNK;

    for (int j = tid; j < OT_PER_B; j += SSORT_THREADS) lh[j] = 0;
    __syncthreads();

    unsigned mK[K1_IPT], ltK[K1_IPT], rkK[K1_IPT];
    float tsK[K1_IPT];

    #pragma unroll
    for (int k = 0; k < K1_IPT; ++k) {
        const int idx = base + k * SSORT_THREADS + tid;
        unsigned lt = 0xFFFFu, rk = 0, m = 0; float t = 0.f;
        if (idx < N) {
            const int i = b * N + idx;
            const int y = ev_y[i];
            const int x = ev_x[i];
            t = ts[i];
            const int p = pol[i];
            lt = (unsigned)((y >> 4) * OTX + (x >> 5));
            rk = atomicAdd(&lh[lt], 1u);
            m = (unsigned)y | ((unsigned)x << 9) | ((unsigned)(p & 1) << 19);
        }
        mK[k] = m; ltK[k] = lt; rkK[k] = rk; tsK[k] = t;
    }
    __syncthreads();

    for (int j = tid; j < OT_PER_B; j += SSORT_THREADS) {
        const unsigned n = lh[j];
        lbase[j] = n ? atomicAdd(&scurs[(size_t)(b * OT_PER_B + j) * SCURS_STRIDE], n)
                     : 0u;
    }
    __syncthreads();

    #pragma unroll
    for (int k = 0; k < K1_IPT; ++k) {
        const unsigned lt = ltK[k];
        if (lt == 0xFFFFu) continue;
        const unsigned slot = lbase[lt] + rkK[k];
        if (slot < (unsigned)cap) {
            uint2 r; r.x = mK[k]; r.y = __float_as_uint(tsK[k]);
            srecs[(size_t)(b * OT_PER_B + lt) * cap + slot] = r;
        } else {
            // rare: process fully now, defer via unrestricted spill
            const int y = (int)(mK[k] & 511u);
            const int x = (int)((mK[k] >> 9) & 1023u);
            const int p = (int)((mK[k] >> 19) & 1u);
            float wy, wx, nts;
            warp_from(flow, b, y, x, tsK[k], wy, wx, nts);
            const unsigned g = atomicAdd(spillcnt, 1u);
            if (g < SPILL_CAP) {
                float4 s; s.x = wy; s.y = wx; s.z = nts;
                s.w = __uint_as_float((unsigned)((b << 1) | p));  // bit31=0
                spill[g] = s;
            }
        }
    }
}

// ---------------------------------------------------------------------------
// K2: 2 blocks per source tile; each handles half the tile's records.
// Flow tile (2 x 16 x 32 floats = 4 KB) preloaded into LDS.
__global__ void __launch_bounds__(256)
build2_kernel(const float* __restrict__ flow,
              const unsigned* __restrict__ scurs, unsigned* __restrict__ dcurs,
              unsigned* __restrict__ spillcnt, float4* __restrict__ spill,
              const uint2* __restrict__ srecs, uint2* __restrict__ drecs,
              int cap) {
    __shared__ unsigned dh[9];
    __shared__ unsigned dbase[9];
    __shared__ float lflow[2][OT_H][OT_W];   // [ch][ly][lx]
    const int tile = blockIdx.x >> 1;
    const int half = blockIdx.x & 1;
    const int tid = threadIdx.x;
    const int b   = tile / OT_PER_B;
    const int lt  = tile % OT_PER_B;
    const int ssy = lt / OTX;
    const int ssx = lt % OTX;

    if (tid < 9) dh[tid] = 0;
    // preload flow tile: 1024 floats over 256 threads
    {
        const float* fb = flow + (size_t)b * 2 * IMG_H * IMG_W;
        #pragma unroll
        for (int j = tid; j < 2 * OT_H * OT_W; j += 256) {
            const int ch = j / (OT_H * OT_W);
            const int r  = (j % (OT_H * OT_W)) / OT_W;
            const int c  = j % OT_W;
            lflow[ch][r][c] = fb[(size_t)ch * IMG_H * IMG_W
                                 + (ssy * OT_H + r) * IMG_W + (ssx * OT_W + c)];
        }
    }
    __syncthreads();

    const unsigned cnt = min(scurs[(size_t)tile * SCURS_STRIDE], (unsigned)cap);
    const unsigned hsz = (cnt + 1u) >> 1;
    const unsigned lo  = half * hsz;
    const unsigned hi  = min(cnt, lo + hsz);
    const uint2* sbase = srecs + (size_t)tile * cap;

    // hsz <= 512 -> 2 iterations
    float wyK[2], wxK[2], ntsK[2];
    unsigned pK[2], ndK[2], relK[2], rk0K[2], rk1K[2], rk2K[2], rk3K[2];

    #pragma unroll
    for (int k = 0; k < 2; ++k) {
        unsigned nd = 0, relp = 0, r0 = 0, r1 = 0, r2 = 0, r3 = 0;
        float wy = 0.f, wx = 0.f, nts = 0.f; unsigned p = 0;
        const unsigned i = lo + (unsigned)(k * 256 + tid);
        if (i < hi) {
            const uint2 sr = sbase[i];
            const int y = (int)(sr.x & 511u);
            const int x = (int)((sr.x >> 9) & 1023u);
            p = (sr.x >> 19) & 1u;
            const float t = __uint_as_float(sr.y);
            const float fx = lflow[0][y & (OT_H - 1)][x & (OT_W - 1)];
            const float fy = lflow[1][y & (OT_H - 1)][x & (OT_W - 1)];
            const float dt = 1.0f - t;
            wy = (float)y + dt * fy;
            wx = (float)x + dt * fx;
            nts = 1.0f - fabsf(1.0f - t);

            const int iy0 = (int)floorf(wy);
            const int ix0 = (int)floorf(wx);
            int rys[2]; int nry = 0;
            if (iy0 >= 0 && iy0 < IMG_H) rys[nry++] = iy0 >> 4;
            if (iy0 + 1 >= 0 && iy0 + 1 < IMG_H) {
                const int r = (iy0 + 1) >> 4;
                if (nry == 0 || r != rys[0]) rys[nry++] = r;
            }
            int rxs[2]; int nrx = 0;
            if (ix0 >= 0 && ix0 < IMG_W) rxs[nrx++] = ix0 >> 5;
            if (ix0 + 1 >= 0 && ix0 + 1 < IMG_W) {
                const int r = (ix0 + 1) >> 5;
                if (nrx == 0 || r != rxs[0]) rxs[nrx++] = r;
            }
            if (nry > 0 && nrx > 0) {
                unsigned rels[4]; unsigned m = 0;
                bool oob = false;
                for (int a = 0; a < nry; ++a)
                    for (int c = 0; c < nrx; ++c) {
                        const int ry_r = rys[a] - ssy + 1;
                        const int rx_r = rxs[c] - ssx + 1;
                        if ((unsigned)ry_r > 2u || (unsigned)rx_r > 2u) {
                            // outside 3x3 ring: restricted spill for this dest
                            oob = true;
                            const unsigned g = atomicAdd(spillcnt, 1u);
                            if (g < SPILL_CAP) {
                                float4 s; s.x = wy; s.y = wx; s.z = nts;
                                s.w = __uint_as_float(0x80000000u
                                        | (unsigned)((b << 1) | p)
                                        | ((unsigned)rys[a] << 8)
                                        | ((unsigned)rxs[c] << 16));
                                spill[g] = s;
                            }
                        } else {
                            rels[m++] = (unsigned)(ry_r * 3 + rx_r);
                        }
                    }
                (void)oob;
                nd = m;
                for (unsigned d = 0; d < m; ++d) {
                    relp |= rels[d] << (8 * d);
                    const unsigned rr = atomicAdd(&dh[rels[d]], 1u);
                    if (d == 0) r0 = rr; else if (d == 1) r1 = rr;
                    else if (d == 2) r2 = rr; else r3 = rr;
                }
            }
        }
        wyK[k] = wy; wxK[k] = wx; ntsK[k] = nts; pK[k] = p;
        ndK[k] = nd; relK[k] = relp;
        rk0K[k] = r0; rk1K[k] = r1; rk2K[k] = r2; rk3K[k] = r3;
    }
    __syncthreads();

    if (tid < 9) {
        const unsigned n = dh[tid];
        if (n) {
            const int dty = ssy + tid / 3 - 1;
            const int dtx = ssx + tid % 3 - 1;
            dbase[tid] = atomicAdd(&dcurs[b * OT_PER_B + dty * OTX + dtx], n);
        }
    }
    __syncthreads();

    #pragma unroll
    for (int k = 0; k < 2; ++k) {
        const unsigned nd = ndK[k];
        for (unsigned d = 0; d < nd; ++d) {
            const unsigned rel = (relK[k] >> (8 * d)) & 0xFFu;
            const unsigned rr = (d == 0) ? rk0K[k] : (d == 1) ? rk1K[k]
                              : (d == 2) ? rk2K[k] : rk3K[k];
            const int dty = ssy + (int)(rel / 3) - 1;
            const int dtx = ssx + (int)(rel % 3) - 1;
            const unsigned slot = dbase[rel] + rr;
            if (slot < (unsigned)cap) {
                int qy = __float2int_rn((wyK[k] - 16.0f * dty + 1.0f) * 2048.0f);
                int qx = __float2int_rn((wxK[k] - 32.0f * dtx + 1.0f) * 1024.0f);
                int qt = __float2int_rn(ntsK[k] * 32767.0f);
                qy = min(max(qy, 0), 65535);
                qx = min(max(qx, 0), 65535);
                qt = min(max(qt, 0), 32767);
                uint2 dr;
                dr.x = (unsigned)qy | ((unsigned)qx << 16);
                dr.y = (unsigned)qt | (pK[k] << 15);
                drecs[(size_t)(b * OT_PER_B + dty * OTX + dtx) * cap + slot] = dr;
            } else {
                // restricted spill: this dest tile only (no double count)
                const unsigned g = atomicAdd(spillcnt, 1u);
                if (g < SPILL_CAP) {
                    float4 s; s.x = wyK[k]; s.y = wxK[k]; s.z = ntsK[k];
                    s.w = __uint_as_float(0x80000000u
                            | (unsigned)((b << 1) | pK[k])
                            | ((unsigned)dty << 8) | ((unsigned)dtx << 16));
                    spill[g] = s;
                }
            }
        }
    }
}

// ---------------------------------------------------------------------------
// K3: one block per ownership tile. Decode 8-B records; accumulate (w, w*nts)
// Q20-packed via ONE ds_add_u64 per corner; fused spill application; pure
// float4 writeout (exclusive ownership -> no out-memset needed).
__global__ void __launch_bounds__(256)
splat_kernel(const uint2* __restrict__ drecs, const unsigned* __restrict__ dcurs,
             const float4* __restrict__ spill, const unsigned* __restrict__ spillcnt,
             float* __restrict__ out, int cap) {
    __shared__ unsigned long long acc64[2 * ACC_PLANE];  // [pol(pos,neg)][cell]
    const int tile = blockIdx.x;
    const int tid = threadIdx.x;
    #pragma unroll
    for (int j = tid; j < 2 * ACC_PLANE; j += 256) acc64[j] = 0ull;
    __syncthreads();

    const int myb = tile / OT_PER_B;
    const int rb  = tile % OT_PER_B;
    const int sy  = rb / OTX;
    const int sx  = rb % OTX;

    const unsigned cnt = min(dcurs[tile], (unsigned)cap);
    const uint2* base = drecs + (size_t)tile * cap;
    for (unsigned i = tid; i < cnt; i += 256) {
        const uint2 r = base[i];
        const float ry  = (float)(r.x & 0xFFFFu) * (1.0f / 2048.0f) - 1.0f;
        const float rx  = (float)(r.x >> 16)     * (1.0f / 1024.0f) - 1.0f;
        const float nts = (float)(r.y & 0x7FFFu) * (1.0f / 32767.0f);
        const int p = (int)((r.y >> 15) & 1u);
        const float byf = floorf(ry), bxf = floorf(rx);
        const int iy0 = (int)byf, ix0 = (int)bxf;
        const float ay = ry - byf, ax = rx - bxf;
        const float wyv[2] = {1.0f - ay, ay};
        const float wxv[2] = {1.0f - ax, ax};
        unsigned long long* accp = acc64 + (p ? 0 : 1) * ACC_PLANE;
        #pragma unroll
        for (int dy = 0; dy < 2; ++dy) {
            const int gy = iy0 + dy;
            if ((unsigned)gy >= (unsigned)OT_H) continue;
            #pragma unroll
            for (int dx = 0; dx < 2; ++dx) {
                const int gx = ix0 + dx;
                if ((unsigned)gx >= (unsigned)OT_W) continue;
                const float w = wyv[dy] * wxv[dx];
                const unsigned qw  = __float2uint_rn(w * Q20);
                const unsigned qwt = __float2uint_rn(w * nts * Q20);
                atomicAdd(&accp[gy * OT_W + gx],
                          ((unsigned long long)qwt << 32) | (unsigned long long)qw);
            }
        }
    }

    // fused spill application (normally zero records)
    const unsigned nsp = min(*spillcnt, (unsigned)SPILL_CAP);
    for (unsigned i = tid; i < nsp; i += 256) {
        const float4 s = spill[i];
        const unsigned meta = __float_as_uint(s.w);
        if ((int)((meta >> 1) & 3u) != myb) continue;
        if (meta & 0x80000000u) {   // restricted to one dest tile
            if ((int)((meta >> 8) & 31u) != sy || (int)((meta >> 16) & 31u) != sx)
                continue;
        }
        const int p = (int)(meta & 1u);
        const float wy = s.x, wx = s.y, nts = s.z;
        const float byf = floorf(wy), bxf = floorf(wx);
        const int iy0 = (int)byf, ix0 = (int)bxf;
        const float ay = wy - byf, ax = wx - bxf;
        const float wyv[2] = {1.0f - ay, ay};
        const float wxv[2] = {1.0f - ax, ax};
        unsigned long long* accp = acc64 + (p ? 0 : 1) * ACC_PLANE;
        #pragma unroll
        for (int dy = 0; dy < 2; ++dy) {
            const int gy = iy0 + dy;
            if ((gy >> 4) != sy) continue;       // ownership (global coords)
            #pragma unroll
            for (int dx = 0; dx < 2; ++dx) {
                const int gx = ix0 + dx;
                if ((gx >> 5) != sx) continue;
                const float w = wyv[dy] * wxv[dx];
                const unsigned qw  = __float2uint_rn(w * Q20);
                const unsigned qwt = __float2uint_rn(w * nts * Q20);
                atomicAdd(&accp[(gy & 15) * OT_W + (gx & 31)],
                          ((unsigned long long)qwt << 32) | (unsigned long long)qw);
            }
        }
    }
    __syncthreads();

    // writeout: 256 groups of 4 cells; each -> one float4 to count plane and
    // one float4 to ts plane. All plain stores.
    const int y0 = sy * OT_H;
    const int x0 = sx * OT_W;
    float* outb = out + (size_t)myb * 4 * IMG_H * IMG_W;
    {
        const int q = tid;                       // 0..255
        const int pl  = q / (ACC_PLANE / 4);     // 0 = pos, 1 = neg
        const int rem = q % (ACC_PLANE / 4);
        const int ry  = rem / (OT_W / 4);
        const int rx4 = rem % (OT_W / 4);
        float4 c4, t4;
        const unsigned long long* cell = acc64 + pl * ACC_PLANE + rem * 4;
        float* c = &c4.x; float* t = &t4.x;
        #pragma unroll
        for (int j = 0; j < 4; ++j) {
            const unsigned long long v = cell[j];
            c[j] = (float)(unsigned)(v & 0xFFFFFFFFull) * INV_Q20;
            t[j] = (float)(unsigned)(v >> 32) * INV_Q20;
        }
        const size_t off = (size_t)(y0 + ry) * IMG_W + x0 + rx4 * 4;
        *(float4*)(outb + (size_t)pl * IMG_H * IMG_W + off) = c4;
        *(float4*)(outb + (size_t)(pl + 2) * IMG_H * IMG_W + off) = t4;
    }
}

// ---------------------------------------------------------------------------
// Last-resort fallback: direct global atomics (needs zeroed out).
__global__ void __launch_bounds__(256)
event_splat_fallback(const float* __restrict__ flow, const float* __restrict__ ts,
                     const int* __restrict__ ev_y, const int* __restrict__ ev_x,
                     const int* __restrict__ pol, float* __restrict__ out,
                     int N, int total) {
    const int i = blockIdx.x * blockDim.x + threadIdx.x;
    if (i >= total) return;
    const int b = i / N;
    float wy, wx, nts;
    warp_from(flow, b, ev_y[i], ev_x[i], ts[i], wy, wx, nts);
    const int p = pol[i];
    const float byf = floorf(wy), bxf = floorf(wx);
    const int iy0 = (int)byf, ix0 = (int)bxf;
    const float ay = wy - byf, ax = wx - bxf;
    const float wyv[2] = {1.0f - ay, ay};
    const float wxv[2] = {1.0f - ax, ax};
    float* out_c = out + ((size_t)b * 4 + (p ? 0 : 1)) * IMG_H * IMG_W;
    float* out_t = out_c + 2 * IMG_H * IMG_W;
    #pragma unroll
    for (int dy = 0; dy < 2; ++dy) {
        const int gy = iy0 + dy;
        if (gy < 0 || gy >= IMG_H) continue;
        #pragma unroll
        for (int dx = 0; dx < 2; ++dx) {
            const int gx = ix0 + dx;
            if (gx < 0 || gx >= IMG_W) continue;
            const float w = wyv[dy] * wxv[dx];
            const int o = gy * IMG_W + gx;
            atomicAdd(out_c + o, w);
            atomicAdd(out_t + o, w * nts);
        }
    }
}

// ---------------------------------------------------------------------------
extern "C" void kernel_launch(void* const* d_in, const int* in_sizes, int n_in,
                              void* d_out, int out_size, void* d_ws, size_t ws_size,
                              hipStream_t stream) {
    const float* flow = (const float*)d_in[0];
    const float* ts   = (const float*)d_in[1];
    const int*   ev_y = (const int*)d_in[2];
    const int*   ev_x = (const int*)d_in[3];
    const int*   pol  = (const int*)d_in[4];
    float* out = (float*)d_out;

    const int total = in_sizes[2];                  // B*N
    const int B = out_size / (4 * IMG_H * IMG_W);
    const int N = total / B;
    char* ws = (char*)d_ws;

    // cap slots per tile: srec (8 B) + drec (8 B) = 16 B/slot/tile.
    int cap = 0;
    if (ws_size > (size_t)WS_RECS)
        cap = (int)((ws_size - WS_RECS) / ((size_t)NT * 16));
    if (cap > 1024) cap = 1024;
    cap &= ~3;

    if (B == NB && cap >= 640) {
        unsigned* scurs    = (unsigned*)(ws + WS_SCURS);
        unsigned* dcurs    = (unsigned*)(ws + WS_DCURS);
        unsigned* spillcnt = (unsigned*)(ws + WS_SPILLCNT);
        float4*   spill    = (float4*)(ws + WS_SPILL);
        uint2*    srecs    = (uint2*)(ws + WS_RECS);
        uint2*    drecs    = (uint2*)(ws + WS_RECS + (size_t)NT * cap * 8);

        hipMemsetAsync(ws, 0, WS_SPILL, stream);    // scurs + dcurs + spillcnt

        dim3 g1((N + K1_CHUNK - 1) / K1_CHUNK, NB);
        ssort_kernel<<<g1, SSORT_THREADS, 0, stream>>>(flow, ts, ev_y, ev_x, pol,
                                                       scurs, spillcnt, spill,
                                                       srecs, N, cap);
        build2_kernel<<<NT * 2, 256, 0, stream>>>(flow, scurs, dcurs, spillcnt,
                                                  spill, srecs, drecs, cap);
        splat_kernel<<<NT, 256, 0, stream>>>(drecs, dcurs, spill, spillcnt,
                                             out, cap);
        return;
    }

    // last resort
    hipMemsetAsync(d_out, 0, (size_t)out_size * sizeof(float), stream);
    const int blocks = (total + 255) / 256;
    event_splat_fallback<<<blocks, 256, 0, stream>>>(flow, ts, ev_y, ev_x, pol,
                                                     out, N, total);
}